// Round 2
// baseline (558.912 us; speedup 1.0000x reference)
//
#include <hip/hip_runtime.h>
#include <cstdint>
#include <cstddef>

// ---- problem constants ----
#define BN_   16
#define SN_   64
#define C_    480
#define T_    8
#define FY_   28
#define FX_   28
#define OS_   8
#define NDF_  256
#define KC_   64
#define M_    1024            // BN*SN rows
#define KD_   30720           // C*OS*OS
#define PLANE_ 784            // FY*FX
#define CT_   (C_*T_*PLANE_)  // per-bn stride in z_vis
#define KS_   32              // split-K factor
#define KCH_  (KD_/KS_)       // 960 (multiple of 64 -> whole channels per split)
#define BK_   16
#define NSTEP_ (KCH_/BK_)     // 60

// ---------------------------------------------------------------------------
// Kernel 1: per-roi sampling tables.
// tabs[roi][axis][bin] = {p0, p1, frac, valid}  (axis 0 = x, 1 = y), fp32.
// Matches torchvision RoIAlign sampling_ratio=1, aligned=True.
// ---------------------------------------------------------------------------
__global__ void tabs_kernel(const float* __restrict__ bboxs, float* __restrict__ tabs) {
    const int i = blockIdx.x * 256 + threadIdx.x;   // 0..2047 = roi*2 + axis
    if (i >= 2 * M_) return;
    const int roi = i >> 1, axis = i & 1;
    const float b1 = bboxs[roi * 4 + axis];
    const float b2 = bboxs[roi * 4 + 2 + axis];
    const float scale = axis ? (28.0f / 1080.0f) : (28.0f / 1920.0f);
    const float lo = b1 * scale - 0.5f;
    const float binw = (b2 * scale - 0.5f - lo) * 0.125f;
    float* o = tabs + ((size_t)roi * 2 + axis) * 32;   // 8 bins x 4 floats
    #pragma unroll
    for (int j = 0; j < 8; ++j) {
        const float pos = lo + ((float)j + 0.5f) * binw;
        const float v = (pos > -1.0f && pos < 28.0f) ? 1.0f : 0.0f;
        const float pc = fminf(fmaxf(pos, 0.0f), 27.0f);
        const float p0 = floorf(pc);
        const float p1 = fminf(p0 + 1.0f, 27.0f);
        o[j * 4 + 0] = p0;
        o[j * 4 + 1] = p1;
        o[j * 4 + 2] = pc - p0;
        o[j * 4 + 3] = v;
    }
}

// ---------------------------------------------------------------------------
// Kernel 2: fused ROI-align + split-K GEMM (fp32 VALU; no fp32 MFMA on CDNA4).
// Block tile: 128 rows x 256 cols, BK=16; grid (M/128, KS) = (8, 32).
// A[row][k] (k = c*64 + by*8 + bx) is computed on the fly into LDS from
// z_vis[:, :, T-1] via the precomputed tables -> no 126 MB roi intermediate.
// Deterministic split-K: each block writes its own partial slice.
// ---------------------------------------------------------------------------
__global__ __launch_bounds__(512)
void gemm_fused(const float* __restrict__ z_vis, const float* __restrict__ W,
                const float* __restrict__ tabs, float* __restrict__ part) {
    __shared__ float  As[BK_][128];   // [k_local][row_local]  8 KB
    __shared__ float  Bs[BK_][NDF_];  // [k_local][n]         16 KB
    __shared__ float4 Tb[128][16];    // roi tables           32 KB

    const int t  = threadIdx.x;       // 512 threads
    const int r0 = blockIdx.x * 128;
    const int kp = blockIdx.y;
    const int kbase = kp * KCH_;

    // stage this block's roi tables (128 rois x 16 float4)
    {
        const float4* tg = (const float4*)(tabs + (size_t)r0 * 64);
        float4* ts = &Tb[0][0];
        for (int e = t; e < 128 * 16; e += 512) ts[e] = tg[e];
    }

    // A-element assignment: thread covers row=t>>2, k_locals akb..akb+3
    const int arow = t >> 2;
    const int akb  = (t & 3) * 4;
    const int bn   = (r0 + arow) >> 6;
    const float* planeA = z_vis + (size_t)bn * CT_ + (size_t)(T_ - 1) * PLANE_;

    // compute-tile assignment: 8x8 per thread, thread grid 16(ty) x 32(tx)
    const int ty = t >> 5;            // 0..15 -> rows ty*8..+7
    const int tx = t & 31;            // 0..31 -> cols tx*8..+7

    float acc[8][8];
    #pragma unroll
    for (int r = 0; r < 8; ++r)
        #pragma unroll
        for (int c = 0; c < 8; ++c) acc[r][c] = 0.0f;

    __syncthreads();   // Tb ready

    for (int ks = 0; ks < NSTEP_; ++ks) {
        const int kg = kbase + ks * BK_;
        const int c  = kg >> 6;          // channel (BK=16 stays within one c)
        const int b0 = kg & 63;          // bin base within the 8x8 grid

        // ---- A staging: bilinear on the fly ----
        {
            const float* pl = planeA + (size_t)c * (T_ * PLANE_);
            const int by = (b0 + akb) >> 3;            // constant over j-span
            const float4 yt = Tb[arow][8 + by];
            const int y0 = (int)yt.x, y1 = (int)yt.y;
            const float ly = yt.z, vy = yt.w;
            const float* py0 = pl + y0 * FX_;
            const float* py1 = pl + y1 * FX_;
            #pragma unroll
            for (int j = 0; j < 4; ++j) {
                const int kl = akb + j;
                const int bx = kl & 7;
                const float4 xt = Tb[arow][bx];
                const int x0 = (int)xt.x, x1 = (int)xt.y;
                const float lx = xt.z, vx = xt.w;
                const float v00 = py0[x0], v01 = py0[x1];
                const float v10 = py1[x0], v11 = py1[x1];
                const float top = v00 + lx * (v01 - v00);
                const float bot = v10 + lx * (v11 - v10);
                As[kl][arow] = (top + ly * (bot - top)) * (vx * vy);
            }
        }

        // ---- B staging: W[kg..kg+15][0..255], coalesced ----
        {
            const float* wg = W + (size_t)kg * NDF_;
            #pragma unroll
            for (int e = 0; e < 8; ++e) {
                const int idx = t + e * 512;            // 0..4095
                ((float*)Bs)[idx] = wg[idx];
            }
        }
        __syncthreads();

        // ---- inner product ----
        #pragma unroll 2
        for (int kl = 0; kl < BK_; ++kl) {
            float a[8], b[8];
            *(float4*)&a[0] = *(const float4*)&As[kl][ty * 8];
            *(float4*)&a[4] = *(const float4*)&As[kl][ty * 8 + 4];
            *(float4*)&b[0] = *(const float4*)&Bs[kl][tx * 8];
            *(float4*)&b[4] = *(const float4*)&Bs[kl][tx * 8 + 4];
            #pragma unroll
            for (int r = 0; r < 8; ++r)
                #pragma unroll
                for (int cc = 0; cc < 8; ++cc)
                    acc[r][cc] += a[r] * b[cc];
        }
        __syncthreads();
    }

    // ---- write this split's partial [128][256] slice ----
    #pragma unroll
    for (int r = 0; r < 8; ++r) {
        float* po = part + ((size_t)kp * M_ + r0 + ty * 8 + r) * NDF_ + tx * 8;
        *(float4*)po       = *(float4*)&acc[r][0];
        *(float4*)(po + 4) = *(float4*)&acc[r][4];
    }
}

// ---------------------------------------------------------------------------
// Kernel 3: reduce split-K partials + spatial term + soft-assignment cluster.
// One block (256 threads) per roi row. Outputs (fp32, concatenated):
//   z [1024][256], s [1024][64], c [1024] (argmax as float).
// ---------------------------------------------------------------------------
__global__ void cluster_kernel(const float* __restrict__ part, const float* __restrict__ bboxs,
                               const float* __restrict__ b_vis, const float* __restrict__ W_spc,
                               const float* __restrict__ b_spc, const float* __restrict__ cent,
                               float* __restrict__ out) {
    const int row = blockIdx.x;
    const int t = threadIdx.x;
    __shared__ float zs[NDF_];
    __shared__ float dd[KC_];
    __shared__ float su[KC_];
    __shared__ float ssum;

    float accv = 0.0f;
    for (int kp = 0; kp < KS_; ++kp)
        accv += part[((size_t)kp * M_ + row) * NDF_ + t];

    const float x1 = bboxs[row * 4 + 0], y1 = bboxs[row * 4 + 1];
    const float x2 = bboxs[row * 4 + 2], y2 = bboxs[row * 4 + 3];
    const float cx = x1 + (x2 - x1) * 0.5f - 960.0f;
    const float cy = y1 + (y2 - y1) * 0.5f - 540.0f;
    const float nrm = sqrtf(cx * cx + cy * cy) / sqrtf(960.0f * 960.0f + 540.0f * 540.0f);

    const float zj = accv + b_vis[t] + nrm * W_spc[t] + b_spc[t];
    zs[t] = zj;
    out[(size_t)row * NDF_ + t] = zj;                       // output 0: z
    __syncthreads();

    if (t < KC_) {
        float d2 = 0.0f;
        const float* ck = cent + (size_t)t * NDF_;
        #pragma unroll 8
        for (int j = 0; j < NDF_; ++j) {
            const float df = zs[j] - ck[j];
            d2 += df * df;
        }
        const float d = sqrtf(d2);
        dd[t] = d;
        su[t] = 1.0f / (1.0f + d);        // ALPHA=1: (1+d)^(-(1+1)/2) = (1+d)^-1
    }
    __syncthreads();

    if (t == 0) {
        float sum = 0.0f;
        for (int k = 0; k < KC_; ++k) sum += su[k];
        int best = 0;
        float bd = dd[0];
        for (int k = 1; k < KC_; ++k)
            if (dd[k] < bd) { bd = dd[k]; best = k; }      // first-min == argmax(s)
        ssum = sum;
        out[(size_t)M_ * NDF_ + (size_t)M_ * KC_ + row] = (float)best;  // output 2: c
    }
    __syncthreads();

    if (t < KC_)
        out[(size_t)M_ * NDF_ + (size_t)row * KC_ + t] = su[t] / ssum;  // output 1: s
}

// ---------------------------------------------------------------------------
extern "C" void kernel_launch(void* const* d_in, const int* in_sizes, int n_in,
                              void* d_out, int out_size, void* d_ws, size_t ws_size,
                              hipStream_t stream) {
    const float* z_vis = (const float*)d_in[0];
    const float* bboxs = (const float*)d_in[1];
    const float* W_vis = (const float*)d_in[2];
    const float* b_vis = (const float*)d_in[3];
    const float* W_spc = (const float*)d_in[4];
    const float* b_spc = (const float*)d_in[5];
    const float* cent  = (const float*)d_in[6];
    float* out = (float*)d_out;

    char* ws = (char*)d_ws;
    float* tabs = (float*)ws;                               // 1024*64*4   =   262,144 B
    float* part = (float*)(ws + 262144);                    // 32*1024*256*4 = 33,554,432 B
    // total ws use: ~33.8 MB; everything written before read, no memset needed.

    tabs_kernel<<<8, 256, 0, stream>>>(bboxs, tabs);
    gemm_fused<<<dim3(M_ / 128, KS_), 512, 0, stream>>>(z_vis, W_vis, tabs, part);
    cluster_kernel<<<M_, 256, 0, stream>>>(part, bboxs, b_vis, W_spc, b_spc, cent, out);
}

// Round 4
// 415.097 us; speedup vs baseline: 1.3465x; 1.3465x over previous
//
#include <hip/hip_runtime.h>
#include <cstdint>
#include <cstddef>

// ---- problem constants ----
#define BN_   16
#define C_    480
#define T_    8
#define FY_   28
#define FX_   28
#define NDF_  256
#define KC_   64
#define M_    1024            // BN*SN rows
#define KD_   30720           // C*8*8
#define PLANE_ 784
#define CHSTRIDE_ (T_*PLANE_) // 6272 floats between channels
#define CT_   (C_*CHSTRIDE_)  // per-bn stride
#define KS_   32              // split-K factor
#define KCH_  960             // K per split (15 whole channels)
#define BK_   32
#define NSTEP_ (KCH_/BK_)     // 30

typedef __attribute__((ext_vector_type(8))) short bf16x8;
typedef __attribute__((ext_vector_type(4))) float f32x4;

__device__ __forceinline__ unsigned rne_bf16(float f) {
    union { float f; unsigned u; } v; v.f = f;
    return v.u + 0x7FFFu + ((v.u >> 16) & 1u);   // RNE; bf16 bits = result >> 16
}
__device__ __forceinline__ float bfbits_to_f(unsigned r) {
    union { unsigned u; float f; } v; v.u = r & 0xFFFF0000u;
    return v.f;
}

// ---------------------------------------------------------------------------
// Kernel 1: W [30720][256] fp32 -> Wt_hi/Wt_lo [256][30720] bf16 (K-contiguous)
// split-bf16: w = hi + lo + O(2^-18 w).  64x64 tiles through LDS.
// ---------------------------------------------------------------------------
__global__ __launch_bounds__(256)
void convert_w(const float* __restrict__ W, unsigned short* __restrict__ Wt_hi,
               unsigned short* __restrict__ Wt_lo) {
    __shared__ unsigned short th[64][68];
    __shared__ unsigned short tl[64][68];
    const int k0 = blockIdx.x * 64, n0 = blockIdx.y * 64;
    const int t = threadIdx.x;
    const int sub = t >> 4, off4 = (t & 15) * 4;
    #pragma unroll
    for (int p = 0; p < 4; ++p) {
        const int kr = p * 16 + sub;
        const float4 v = *(const float4*)&W[(size_t)(k0 + kr) * NDF_ + n0 + off4];
        const float vv[4] = { v.x, v.y, v.z, v.w };
        #pragma unroll
        for (int e = 0; e < 4; ++e) {
            const unsigned rh = rne_bf16(vv[e]);
            const unsigned rl = rne_bf16(vv[e] - bfbits_to_f(rh));
            th[kr][off4 + e] = (unsigned short)(rh >> 16);
            tl[kr][off4 + e] = (unsigned short)(rl >> 16);
        }
    }
    __syncthreads();
    #pragma unroll
    for (int p = 0; p < 4; ++p) {
        const int nr = p * 16 + sub;
        ushort4 oh, ol;
        oh.x = th[off4 + 0][nr]; oh.y = th[off4 + 1][nr];
        oh.z = th[off4 + 2][nr]; oh.w = th[off4 + 3][nr];
        ol.x = tl[off4 + 0][nr]; ol.y = tl[off4 + 1][nr];
        ol.z = tl[off4 + 2][nr]; ol.w = tl[off4 + 3][nr];
        *(ushort4*)&Wt_hi[(size_t)(n0 + nr) * KD_ + k0 + off4] = oh;
        *(ushort4*)&Wt_lo[(size_t)(n0 + nr) * KD_ + k0 + off4] = ol;
    }
}

// ---------------------------------------------------------------------------
// Kernel 2: cent [64][256] -> centT [256][64] fp32 (coalesced distance reads)
// ---------------------------------------------------------------------------
__global__ void convert_cent(const float* __restrict__ cent, float* __restrict__ centT) {
    const int j = threadIdx.x;   // 0..255
    for (int k = 0; k < KC_; ++k)
        centT[(size_t)j * KC_ + k] = cent[(size_t)k * NDF_ + j];
}

// ---------------------------------------------------------------------------
// Kernel 3: fused ROI-align + split-bf16 (3-product) MFMA split-K GEMM.
// Tile 64 rows x 256 cols, BK=32; grid (16 m-tiles, 32 k-splits) = 512 blocks.
// acc += Ah*Bh + Al*Bh + Ah*Bl  (fp32 AGPR accumulate; drops only al*bl).
// A generated on the fly (bilinear fp32 -> hi/lo bf16) into LDS;
// B staged via global_load_lds width=16 from K-contiguous Wt_hi/Wt_lo.
// ---------------------------------------------------------------------------
__global__ __launch_bounds__(256)
void gemm_fused(const float* __restrict__ z_vis, const unsigned short* __restrict__ Wt_hi,
                const unsigned short* __restrict__ Wt_lo, const float* __restrict__ bboxs,
                float* __restrict__ part) {
    __shared__ short Ah[64 * 32];            // 4 KB
    __shared__ short Al[64 * 32];            // 4 KB
    __shared__ unsigned short Bh[256 * 32];  // 16 KB
    __shared__ unsigned short Bl[256 * 32];  // 16 KB
    const int t = threadIdx.x;
    const int mi = blockIdx.x, ks = blockIdx.y;
    const int lane = t & 63, wid = t >> 6;
    const int m = t >> 2, kgroup = t & 3;    // A-gen: row m, k-octet kgroup
    const int roi = mi * 64 + m;
    const int kbase = ks * KCH_;

    // per-thread x-sampling table (registers) + y params
    float lo_y, binw_y;
    int xi0[8], xi1[8];
    float xw0[8], xw1[8];
    {
        const float bx1 = bboxs[roi * 4 + 0], by1 = bboxs[roi * 4 + 1];
        const float bx2 = bboxs[roi * 4 + 2], by2 = bboxs[roi * 4 + 3];
        const float sx = 28.0f / 1920.0f, sy = 28.0f / 1080.0f;
        const float lo_x = bx1 * sx - 0.5f;
        const float binw_x = (bx2 * sx - 0.5f - lo_x) * 0.125f;
        lo_y = by1 * sy - 0.5f;
        binw_y = (by2 * sy - 0.5f - lo_y) * 0.125f;
        #pragma unroll
        for (int b = 0; b < 8; ++b) {
            const float pos = lo_x + ((float)b + 0.5f) * binw_x;
            const float vx = (pos > -1.0f && pos < 28.0f) ? 1.0f : 0.0f;
            const float pc = fminf(fmaxf(pos, 0.0f), 27.0f);
            const float p0 = floorf(pc);
            const float lx = pc - p0;
            xi0[b] = (int)p0;
            xi1[b] = min(xi0[b] + 1, 27);
            xw0[b] = vx * (1.0f - lx);
            xw1[b] = vx * lx;
        }
    }
    // all 64 rois in this block share bn == mi
    const float* plane = z_vis + (size_t)mi * CT_ + (size_t)(T_ - 1) * PLANE_;

    const int brow_l = lane >> 2;          // B-staging lane->row
    const int bkoff = (lane & 3) * 8;      // B-staging lane->k offset (elems)

    f32x4 acc[4][4] = {};

    for (int s = 0; s < NSTEP_; ++s) {
        // ---- issue B DMA first (overlaps A-gen VALU) ----
        #pragma unroll
        for (int q = 0; q < 4; ++q) {
            const int rbase = q * 64 + wid * 16;               // wave-uniform
            const size_t goff = (size_t)(rbase + brow_l) * KD_ + kbase + s * BK_ + bkoff;
            __builtin_amdgcn_global_load_lds(
                (const __attribute__((address_space(1))) void*)(Wt_hi + goff),
                (__attribute__((address_space(3))) void*)&Bh[rbase * 32], 16, 0, 0);
            __builtin_amdgcn_global_load_lds(
                (const __attribute__((address_space(1))) void*)(Wt_lo + goff),
                (__attribute__((address_space(3))) void*)&Bl[rbase * 32], 16, 0, 0);
        }

        // ---- A-gen: 8 bilinear samples -> hi/lo bf16 -> LDS ----
        const int cch = (kbase + s * BK_) >> 6;                // channel (step-uniform)
        const float* pl = plane + (size_t)cch * CHSTRIDE_;
        const int by = ((s * BK_ + kgroup * 8) >> 3) & 7;
        const float posy = lo_y + ((float)by + 0.5f) * binw_y;
        const float vy = (posy > -1.0f && posy < 28.0f) ? 1.0f : 0.0f;
        const float pcy = fminf(fmaxf(posy, 0.0f), 27.0f);
        const float py0f = floorf(pcy);
        const float ly = pcy - py0f;
        const int y0 = (int)py0f, y1 = min(y0 + 1, 27);
        const float wy0 = vy * (1.0f - ly), wy1 = vy * ly;
        const float* r0p = pl + y0 * FX_;
        const float* r1p = pl + y1 * FX_;
        unsigned ph[4], plo[4];
        #pragma unroll
        for (int p = 0; p < 4; ++p) {
            unsigned rh[2], rl[2];
            #pragma unroll
            for (int h = 0; h < 2; ++h) {
                const int b = p * 2 + h;
                const float v00 = r0p[xi0[b]], v01 = r0p[xi1[b]];
                const float v10 = r1p[xi0[b]], v11 = r1p[xi1[b]];
                const float val = wy0 * (xw0[b] * v00 + xw1[b] * v01)
                                + wy1 * (xw0[b] * v10 + xw1[b] * v11);
                rh[h] = rne_bf16(val);
                rl[h] = rne_bf16(val - bfbits_to_f(rh[h]));
            }
            ph[p]  = __builtin_amdgcn_perm(rh[1], rh[0], 0x07060302u);
            plo[p] = __builtin_amdgcn_perm(rl[1], rl[0], 0x07060302u);
        }
        *(uint4*)&Ah[m * 32 + kgroup * 8] = make_uint4(ph[0], ph[1], ph[2], ph[3]);
        *(uint4*)&Al[m * 32 + kgroup * 8] = make_uint4(plo[0], plo[1], plo[2], plo[3]);

        __syncthreads();   // drains ds_write (lgkm) + global_load_lds (vmcnt)

        // ---- fragments + 3-product MFMA ----
        const int fr = lane & 15, fq = lane >> 4;
        bf16x8 afh[4], afl[4];
        #pragma unroll
        for (int i = 0; i < 4; ++i) {
            afh[i] = *(const bf16x8*)&Ah[(i * 16 + fr) * 32 + fq * 8];
            afl[i] = *(const bf16x8*)&Al[(i * 16 + fr) * 32 + fq * 8];
        }
        #pragma unroll
        for (int j = 0; j < 4; ++j) {
            const bf16x8 bh = *(const bf16x8*)&Bh[(wid * 64 + j * 16 + fr) * 32 + fq * 8];
            const bf16x8 bl = *(const bf16x8*)&Bl[(wid * 64 + j * 16 + fr) * 32 + fq * 8];
            #pragma unroll
            for (int i = 0; i < 4; ++i) {
                acc[i][j] = __builtin_amdgcn_mfma_f32_16x16x32_bf16(afh[i], bh, acc[i][j], 0, 0, 0);
                acc[i][j] = __builtin_amdgcn_mfma_f32_16x16x32_bf16(afl[i], bh, acc[i][j], 0, 0, 0);
                acc[i][j] = __builtin_amdgcn_mfma_f32_16x16x32_bf16(afh[i], bl, acc[i][j], 0, 0, 0);
            }
        }
        __syncthreads();
    }

    // ---- write split partial; C/D: col=lane&15, row=(lane>>4)*4+r ----
    const int fr = lane & 15, fq = lane >> 4;
    float* pb = part + (size_t)ks * M_ * NDF_;
    #pragma unroll
    for (int i = 0; i < 4; ++i) {
        const int row = mi * 64 + i * 16 + fq * 4;
        #pragma unroll
        for (int j = 0; j < 4; ++j) {
            const int col = wid * 64 + j * 16 + fr;
            #pragma unroll
            for (int r = 0; r < 4; ++r)
                pb[(size_t)(row + r) * NDF_ + col] = acc[i][j][r];
        }
    }
}

// ---------------------------------------------------------------------------
// Kernel 4: reduce split-K + spatial term + soft-assignment clustering.
// 1024 blocks x 256 threads. Distances 4-way parallel with coalesced centT.
// ---------------------------------------------------------------------------
__global__ __launch_bounds__(256)
void cluster_kernel(const float* __restrict__ part, const float* __restrict__ bboxs,
                    const float* __restrict__ b_vis, const float* __restrict__ W_spc,
                    const float* __restrict__ b_spc, const float* __restrict__ centT,
                    float* __restrict__ out) {
    const int row = blockIdx.x, t = threadIdx.x;
    __shared__ float zs[NDF_];
    __shared__ float dp[4][KC_];

    float a = 0.0f;
    #pragma unroll
    for (int kp = 0; kp < KS_; ++kp)
        a += part[(size_t)kp * M_ * NDF_ + (size_t)row * NDF_ + t];

    const float x1 = bboxs[row * 4 + 0], y1 = bboxs[row * 4 + 1];
    const float x2 = bboxs[row * 4 + 2], y2 = bboxs[row * 4 + 3];
    const float cx = x1 + (x2 - x1) * 0.5f - 960.0f;
    const float cy = y1 + (y2 - y1) * 0.5f - 540.0f;
    const float nrm = sqrtf(cx * cx + cy * cy) / sqrtf(960.0f * 960.0f + 540.0f * 540.0f);

    const float zj = a + b_vis[t] + nrm * W_spc[t] + b_spc[t];
    zs[t] = zj;
    out[(size_t)row * NDF_ + t] = zj;                         // output 0: z
    __syncthreads();

    const int k = t & 63, q = t >> 6;
    {
        float d2 = 0.0f;
        const float* ct = centT + (size_t)q * 64 * KC_;
        #pragma unroll 8
        for (int j = 0; j < 64; ++j) {
            const float df = zs[q * 64 + j] - ct[(size_t)j * KC_ + k];
            d2 += df * df;
        }
        dp[q][k] = d2;
    }
    __syncthreads();

    if (t < 64) {
        const float d = sqrtf(dp[0][t] + dp[1][t] + dp[2][t] + dp[3][t]);
        const float su = 1.0f / (1.0f + d);                   // ALPHA=1
        float sum = su;
        #pragma unroll
        for (int mk = 1; mk < 64; mk <<= 1) sum += __shfl_xor(sum, mk, 64);
        out[(size_t)M_ * NDF_ + (size_t)row * KC_ + t] = su / sum;   // output 1: s
        float v = d; int idx = t;
        #pragma unroll
        for (int mk = 1; mk < 64; mk <<= 1) {
            const float ov = __shfl_xor(v, mk, 64);
            const int oi = __shfl_xor(idx, mk, 64);
            if (ov < v || (ov == v && oi < idx)) { v = ov; idx = oi; }
        }
        if (t == 0)
            out[(size_t)M_ * NDF_ + (size_t)M_ * KC_ + row] = (float)idx;  // output 2: c
    }
}

// ---------------------------------------------------------------------------
extern "C" void kernel_launch(void* const* d_in, const int* in_sizes, int n_in,
                              void* d_out, int out_size, void* d_ws, size_t ws_size,
                              hipStream_t stream) {
    const float* z_vis = (const float*)d_in[0];
    const float* bboxs = (const float*)d_in[1];
    const float* W_vis = (const float*)d_in[2];
    const float* b_vis = (const float*)d_in[3];
    const float* W_spc = (const float*)d_in[4];
    const float* b_spc = (const float*)d_in[5];
    const float* cent  = (const float*)d_in[6];
    float* out = (float*)d_out;

    char* ws = (char*)d_ws;
    unsigned short* Wt_hi = (unsigned short*)ws;                          // 15,728,640 B
    unsigned short* Wt_lo = (unsigned short*)(ws + 15728640);             // 15,728,640 B
    float*          centT = (float*)(ws + 2 * 15728640);                  //     65,536 B
    float*          part  = (float*)(ws + 2 * 15728640 + 65536);          // 33,554,432 B
    // total ws: ~65 MB; all written before read.

    convert_w<<<dim3(KD_ / 64, NDF_ / 64), 256, 0, stream>>>(W_vis, Wt_hi, Wt_lo);
    convert_cent<<<1, 256, 0, stream>>>(cent, centT);
    gemm_fused<<<dim3(M_ / 64, KS_), 256, 0, stream>>>(z_vis, Wt_hi, Wt_lo, bboxs, part);
    cluster_kernel<<<M_, 256, 0, stream>>>(part, bboxs, b_vis, W_spc, b_spc, centT, out);
}

// Round 5
// 413.339 us; speedup vs baseline: 1.3522x; 1.0043x over previous
//
#include <hip/hip_runtime.h>
#include <cstdint>
#include <cstddef>

// ---- problem constants ----
#define BN_   16
#define C_    480
#define T_    8
#define FY_   28
#define FX_   28
#define NDF_  256
#define KC_   64
#define M_    1024            // BN*SN rows
#define KD_   30720           // C*8*8
#define PLANE_ 784
#define CHSTRIDE_ (T_*PLANE_) // 6272 floats between channels
#define CT_   (C_*CHSTRIDE_)  // per-bn stride
#define KS_   32              // split-K factor
#define KCH_  960             // K per split (15 whole channels)
#define BK_   32
#define NSTEP_ (KCH_/BK_)     // 30
#define MT_   32              // M-tile (rows per block)
#define APAD_ 40              // A LDS row stride (elems) — conflict-breaking pad

typedef __attribute__((ext_vector_type(8))) short bf16x8;
typedef __attribute__((ext_vector_type(4))) float f32x4;

__device__ __forceinline__ unsigned rne_bf16(float f) {
    union { float f; unsigned u; } v; v.f = f;
    return v.u + 0x7FFFu + ((v.u >> 16) & 1u);   // RNE; bf16 bits = result >> 16
}
__device__ __forceinline__ float bfbits_to_f(unsigned r) {
    union { unsigned u; float f; } v; v.u = r & 0xFFFF0000u;
    return v.f;
}

// ---------------------------------------------------------------------------
// Kernel 1: W [30720][256] fp32 -> Wt_hi/Wt_lo [256][30720] bf16 (K-contiguous)
// ---------------------------------------------------------------------------
__global__ __launch_bounds__(256)
void convert_w(const float* __restrict__ W, unsigned short* __restrict__ Wt_hi,
               unsigned short* __restrict__ Wt_lo) {
    __shared__ unsigned short th[64][68];
    __shared__ unsigned short tl[64][68];
    const int k0 = blockIdx.x * 64, n0 = blockIdx.y * 64;
    const int t = threadIdx.x;
    const int sub = t >> 4, off4 = (t & 15) * 4;
    #pragma unroll
    for (int p = 0; p < 4; ++p) {
        const int kr = p * 16 + sub;
        const float4 v = *(const float4*)&W[(size_t)(k0 + kr) * NDF_ + n0 + off4];
        const float vv[4] = { v.x, v.y, v.z, v.w };
        #pragma unroll
        for (int e = 0; e < 4; ++e) {
            const unsigned rh = rne_bf16(vv[e]);
            const unsigned rl = rne_bf16(vv[e] - bfbits_to_f(rh));
            th[kr][off4 + e] = (unsigned short)(rh >> 16);
            tl[kr][off4 + e] = (unsigned short)(rl >> 16);
        }
    }
    __syncthreads();
    #pragma unroll
    for (int p = 0; p < 4; ++p) {
        const int nr = p * 16 + sub;
        ushort4 oh, ol;
        oh.x = th[off4 + 0][nr]; oh.y = th[off4 + 1][nr];
        oh.z = th[off4 + 2][nr]; oh.w = th[off4 + 3][nr];
        ol.x = tl[off4 + 0][nr]; ol.y = tl[off4 + 1][nr];
        ol.z = tl[off4 + 2][nr]; ol.w = tl[off4 + 3][nr];
        *(ushort4*)&Wt_hi[(size_t)(n0 + nr) * KD_ + k0 + off4] = oh;
        *(ushort4*)&Wt_lo[(size_t)(n0 + nr) * KD_ + k0 + off4] = ol;
    }
}

// ---------------------------------------------------------------------------
// Kernel 2: cent [64][256] -> centT [256][64] fp32 (parallel over k)
// ---------------------------------------------------------------------------
__global__ void convert_cent(const float* __restrict__ cent, float* __restrict__ centT) {
    const int k = blockIdx.x;       // 0..63
    const int j = threadIdx.x;      // 0..255
    centT[(size_t)j * KC_ + k] = cent[(size_t)k * NDF_ + j];
}

// ---------------------------------------------------------------------------
// Kernel 3: fused ROI-align + split-bf16 (3-product) MFMA split-K GEMM.
// Tile 32 rows x 256 cols, BK=32; grid (ks=32, mi=32) = 1024 blocks = 4/CU.
// blockIdx.x = ks so same-B-slice blocks co-reside on one XCD (L2 locality).
// Pipelined: frags -> regs between barriers; next-step DMA/A-gen issued
// before MFMA so the barrier-1 vmcnt drain overlaps compute.
// ---------------------------------------------------------------------------
__global__ __launch_bounds__(256, 4)
void gemm_fused(const float* __restrict__ z_vis, const unsigned short* __restrict__ Wt_hi,
                const unsigned short* __restrict__ Wt_lo, const float* __restrict__ bboxs,
                float* __restrict__ part) {
    __shared__ short Ah[MT_ * APAD_];        // 2.5 KB (padded stride 40)
    __shared__ short Al[MT_ * APAD_];        // 2.5 KB
    __shared__ unsigned short Bh[256 * 32];  // 16 KB
    __shared__ unsigned short Bl[256 * 32];  // 16 KB
    const int t = threadIdx.x;
    const int ks = blockIdx.x, mi = blockIdx.y;
    const int lane = t & 63, wid = t >> 6;
    const int kbase = ks * KCH_;

    // ---- A-gen assignment: row m = t>>3, k-quad q = t&7 (4 samples each) ----
    const int m = t >> 3, q = t & 7;
    const int roi = mi * MT_ + m;
    const int bn = mi >> 1;                  // 32 rois per block share one bn

    // x-sampling entries for this thread's 4 bins: bx = (q&1)*4 + j
    int xi0[4], xi1[4];
    float xw0[4], xw1[4];
    // y param sets for s even (by = q>>1) and s odd (by = 4 + (q>>1))
    int ye0, ye1, yo0, yo1;
    float ywe0, ywe1, ywo0, ywo1;
    {
        const float bx1 = bboxs[roi * 4 + 0], by1 = bboxs[roi * 4 + 1];
        const float bx2 = bboxs[roi * 4 + 2], by2 = bboxs[roi * 4 + 3];
        const float sx = 28.0f / 1920.0f, sy = 28.0f / 1080.0f;
        const float lo_x = bx1 * sx - 0.5f;
        const float binw_x = (bx2 * sx - 0.5f - lo_x) * 0.125f;
        const float lo_y = by1 * sy - 0.5f;
        const float binw_y = (by2 * sy - 0.5f - lo_y) * 0.125f;
        #pragma unroll
        for (int j = 0; j < 4; ++j) {
            const int b = (q & 1) * 4 + j;
            const float pos = lo_x + ((float)b + 0.5f) * binw_x;
            const float vx = (pos > -1.0f && pos < 28.0f) ? 1.0f : 0.0f;
            const float pc = fminf(fmaxf(pos, 0.0f), 27.0f);
            const float p0 = floorf(pc);
            const float lx = pc - p0;
            xi0[j] = (int)p0;
            xi1[j] = min(xi0[j] + 1, 27);
            xw0[j] = vx * (1.0f - lx);
            xw1[j] = vx * lx;
        }
        #pragma unroll
        for (int par = 0; par < 2; ++par) {
            const int by = par * 4 + (q >> 1);
            const float pos = lo_y + ((float)by + 0.5f) * binw_y;
            const float vy = (pos > -1.0f && pos < 28.0f) ? 1.0f : 0.0f;
            const float pc = fminf(fmaxf(pos, 0.0f), 27.0f);
            const float p0 = floorf(pc);
            const float ly = pc - p0;
            const int y0 = (int)p0, y1 = min(y0 + 1, 27);
            const float w0 = vy * (1.0f - ly), w1 = vy * ly;
            if (par == 0) { ye0 = y0; ye1 = y1; ywe0 = w0; ywe1 = w1; }
            else          { yo0 = y0; yo1 = y1; ywo0 = w0; ywo1 = w1; }
        }
    }
    const float* plane = z_vis + (size_t)bn * CT_ + (size_t)(T_ - 1) * PLANE_;

    const int brow_l = lane >> 2;            // B-staging lane->row-in-chunk
    const int bkoff = (lane & 3) * 8;        // B-staging lane->k offset (elems)

    // ---- staging lambdas ----
    auto stage_B = [&](int s) {
        #pragma unroll
        for (int qq = 0; qq < 4; ++qq) {
            const int rbase = qq * 64 + wid * 16;           // wave-uniform
            const size_t goff = (size_t)(rbase + brow_l) * KD_ + kbase + s * BK_ + bkoff;
            __builtin_amdgcn_global_load_lds(
                (const __attribute__((address_space(1))) void*)(Wt_hi + goff),
                (__attribute__((address_space(3))) void*)&Bh[rbase * 32], 16, 0, 0);
            __builtin_amdgcn_global_load_lds(
                (const __attribute__((address_space(1))) void*)(Wt_lo + goff),
                (__attribute__((address_space(3))) void*)&Bl[rbase * 32], 16, 0, 0);
        }
    };
    auto stage_A = [&](int s) {
        const int cch = ks * 15 + (s >> 1);                 // channel index
        const float* pl = plane + (size_t)cch * CHSTRIDE_;
        const int sodd = s & 1;
        const int y0 = sodd ? yo0 : ye0, y1 = sodd ? yo1 : ye1;
        const float wy0 = sodd ? ywo0 : ywe0, wy1 = sodd ? ywo1 : ywe1;
        const float* r0p = pl + y0 * FX_;
        const float* r1p = pl + y1 * FX_;
        unsigned rh[4], rl[4];
        #pragma unroll
        for (int j = 0; j < 4; ++j) {
            const float v00 = r0p[xi0[j]], v01 = r0p[xi1[j]];
            const float v10 = r1p[xi0[j]], v11 = r1p[xi1[j]];
            const float val = wy0 * (xw0[j] * v00 + xw1[j] * v01)
                            + wy1 * (xw0[j] * v10 + xw1[j] * v11);
            rh[j] = rne_bf16(val);
            rl[j] = rne_bf16(val - bfbits_to_f(rh[j]));
        }
        const unsigned ph0 = __builtin_amdgcn_perm(rh[1], rh[0], 0x07060302u);
        const unsigned ph1 = __builtin_amdgcn_perm(rh[3], rh[2], 0x07060302u);
        const unsigned pl0 = __builtin_amdgcn_perm(rl[1], rl[0], 0x07060302u);
        const unsigned pl1 = __builtin_amdgcn_perm(rl[3], rl[2], 0x07060302u);
        *(uint2*)&Ah[m * APAD_ + q * 4] = make_uint2(ph0, ph1);
        *(uint2*)&Al[m * APAD_ + q * 4] = make_uint2(pl0, pl1);
    };

    f32x4 acc[2][4] = {};
    const int fr = lane & 15, fq = lane >> 4;

    stage_B(0);
    stage_A(0);

    for (int s = 0; s < NSTEP_; ++s) {
        __syncthreads();                    // staging(s) landed (vmcnt+lgkm drained)

        // ---- fragments -> registers ----
        bf16x8 afh[2], afl[2], bh[4], bl[4];
        #pragma unroll
        for (int i = 0; i < 2; ++i) {
            afh[i] = *(const bf16x8*)&Ah[(i * 16 + fr) * APAD_ + fq * 8];
            afl[i] = *(const bf16x8*)&Al[(i * 16 + fr) * APAD_ + fq * 8];
        }
        #pragma unroll
        for (int j = 0; j < 4; ++j) {
            bh[j] = *(const bf16x8*)&Bh[(wid * 64 + j * 16 + fr) * 32 + fq * 8];
            bl[j] = *(const bf16x8*)&Bl[(wid * 64 + j * 16 + fr) * 32 + fq * 8];
        }
        __syncthreads();                    // all reads done; LDS reusable

        if (s + 1 < NSTEP_) {               // issue next staging BEFORE compute
            stage_B(s + 1);
            stage_A(s + 1);
        }

        // ---- 3-product MFMA (overlaps next-step DMA flight) ----
        #pragma unroll
        for (int j = 0; j < 4; ++j)
            #pragma unroll
            for (int i = 0; i < 2; ++i) {
                acc[i][j] = __builtin_amdgcn_mfma_f32_16x16x32_bf16(afh[i], bh[j], acc[i][j], 0, 0, 0);
                acc[i][j] = __builtin_amdgcn_mfma_f32_16x16x32_bf16(afl[i], bh[j], acc[i][j], 0, 0, 0);
                acc[i][j] = __builtin_amdgcn_mfma_f32_16x16x32_bf16(afh[i], bl[j], acc[i][j], 0, 0, 0);
            }
    }

    // ---- write split partial; C/D: col=lane&15, row=(lane>>4)*4+r ----
    float* pb = part + (size_t)ks * M_ * NDF_;
    #pragma unroll
    for (int i = 0; i < 2; ++i) {
        const int row = mi * MT_ + i * 16 + fq * 4;
        #pragma unroll
        for (int j = 0; j < 4; ++j) {
            const int col = wid * 64 + j * 16 + fr;
            #pragma unroll
            for (int r = 0; r < 4; ++r)
                pb[(size_t)(row + r) * NDF_ + col] = acc[i][j][r];
        }
    }
}

// ---------------------------------------------------------------------------
// Kernel 4: reduce split-K + spatial term + soft-assignment clustering.
// ---------------------------------------------------------------------------
__global__ __launch_bounds__(256)
void cluster_kernel(const float* __restrict__ part, const float* __restrict__ bboxs,
                    const float* __restrict__ b_vis, const float* __restrict__ W_spc,
                    const float* __restrict__ b_spc, const float* __restrict__ centT,
                    float* __restrict__ out) {
    const int row = blockIdx.x, t = threadIdx.x;
    __shared__ float zs[NDF_];
    __shared__ float dp[4][KC_];

    float a = 0.0f;
    #pragma unroll
    for (int kp = 0; kp < KS_; ++kp)
        a += part[(size_t)kp * M_ * NDF_ + (size_t)row * NDF_ + t];

    const float x1 = bboxs[row * 4 + 0], y1 = bboxs[row * 4 + 1];
    const float x2 = bboxs[row * 4 + 2], y2 = bboxs[row * 4 + 3];
    const float cx = x1 + (x2 - x1) * 0.5f - 960.0f;
    const float cy = y1 + (y2 - y1) * 0.5f - 540.0f;
    const float nrm = sqrtf(cx * cx + cy * cy) / sqrtf(960.0f * 960.0f + 540.0f * 540.0f);

    const float zj = a + b_vis[t] + nrm * W_spc[t] + b_spc[t];
    zs[t] = zj;
    out[(size_t)row * NDF_ + t] = zj;                         // output 0: z
    __syncthreads();

    const int k = t & 63, qq = t >> 6;
    {
        float d2 = 0.0f;
        const float* ct = centT + (size_t)qq * 64 * KC_;
        #pragma unroll 8
        for (int j = 0; j < 64; ++j) {
            const float df = zs[qq * 64 + j] - ct[(size_t)j * KC_ + k];
            d2 += df * df;
        }
        dp[qq][k] = d2;
    }
    __syncthreads();

    if (t < 64) {
        const float d = sqrtf(dp[0][t] + dp[1][t] + dp[2][t] + dp[3][t]);
        const float su = 1.0f / (1.0f + d);                   // ALPHA=1
        float sum = su;
        #pragma unroll
        for (int mk = 1; mk < 64; mk <<= 1) sum += __shfl_xor(sum, mk, 64);
        out[(size_t)M_ * NDF_ + (size_t)row * KC_ + t] = su / sum;   // output 1: s
        float v = d; int idx = t;
        #pragma unroll
        for (int mk = 1; mk < 64; mk <<= 1) {
            const float ov = __shfl_xor(v, mk, 64);
            const int oi = __shfl_xor(idx, mk, 64);
            if (ov < v || (ov == v && oi < idx)) { v = ov; idx = oi; }
        }
        if (t == 0)
            out[(size_t)M_ * NDF_ + (size_t)M_ * KC_ + row] = (float)idx;  // output 2: c
    }
}

// ---------------------------------------------------------------------------
extern "C" void kernel_launch(void* const* d_in, const int* in_sizes, int n_in,
                              void* d_out, int out_size, void* d_ws, size_t ws_size,
                              hipStream_t stream) {
    const float* z_vis = (const float*)d_in[0];
    const float* bboxs = (const float*)d_in[1];
    const float* W_vis = (const float*)d_in[2];
    const float* b_vis = (const float*)d_in[3];
    const float* W_spc = (const float*)d_in[4];
    const float* b_spc = (const float*)d_in[5];
    const float* cent  = (const float*)d_in[6];
    float* out = (float*)d_out;

    char* ws = (char*)d_ws;
    unsigned short* Wt_hi = (unsigned short*)ws;                          // 15,728,640 B
    unsigned short* Wt_lo = (unsigned short*)(ws + 15728640);             // 15,728,640 B
    float*          centT = (float*)(ws + 2 * 15728640);                  //     65,536 B
    float*          part  = (float*)(ws + 2 * 15728640 + 65536);          // 33,554,432 B
    // total ws: ~65 MB; all written before read.

    convert_w<<<dim3(KD_ / 64, NDF_ / 64), 256, 0, stream>>>(W_vis, Wt_hi, Wt_lo);
    convert_cent<<<KC_, 256, 0, stream>>>(cent, centT);
    gemm_fused<<<dim3(KS_, M_ / MT_), 256, 0, stream>>>(z_vis, Wt_hi, Wt_lo, bboxs, part);
    cluster_kernel<<<M_, 256, 0, stream>>>(part, bboxs, b_vis, W_spc, b_spc, centT, out);
}

// Round 6
// 408.324 us; speedup vs baseline: 1.3688x; 1.0123x over previous
//
#include <hip/hip_runtime.h>
#include <cstdint>
#include <cstddef>

// ---- problem constants ----
#define BN_   16
#define C_    480
#define T_    8
#define FY_   28
#define FX_   28
#define NDF_  256
#define KC_   64
#define M_    1024            // BN*SN rows
#define KD_   30720           // C*8*8
#define PLANE_ 784
#define CHSTRIDE_ (T_*PLANE_) // 6272 floats between channels
#define CT_   (C_*CHSTRIDE_)  // per-bn stride
#define KS_   32              // split-K factor
#define KCH_  960             // K per split (15 whole channels)
#define NCH_  15              // channels per split
#define MT_   32              // M-tile (rois per block)
#define APAD_ 72              // A LDS row stride (ushorts): 64 + 8 pad

typedef __attribute__((ext_vector_type(8))) short bf16x8;
typedef __attribute__((ext_vector_type(4))) float f32x4;

__device__ __forceinline__ unsigned rne_bf16(float f) {
    union { float f; unsigned u; } v; v.f = f;
    return v.u + 0x7FFFu + ((v.u >> 16) & 1u);   // RNE; bf16 bits = result >> 16
}
__device__ __forceinline__ float bfbits_to_f(unsigned r) {
    union { unsigned u; float f; } v; v.u = r & 0xFFFF0000u;
    return v.f;
}

// ---------------------------------------------------------------------------
// Kernel 1: W [30720][256] fp32 -> Wt_hi/Wt_lo [256][30720] bf16 (K-contiguous)
// ---------------------------------------------------------------------------
__global__ __launch_bounds__(256)
void convert_w(const float* __restrict__ W, unsigned short* __restrict__ Wt_hi,
               unsigned short* __restrict__ Wt_lo) {
    __shared__ unsigned short th[64][68];
    __shared__ unsigned short tl[64][68];
    const int k0 = blockIdx.x * 64, n0 = blockIdx.y * 64;
    const int t = threadIdx.x;
    const int sub = t >> 4, off4 = (t & 15) * 4;
    #pragma unroll
    for (int p = 0; p < 4; ++p) {
        const int kr = p * 16 + sub;
        const float4 v = *(const float4*)&W[(size_t)(k0 + kr) * NDF_ + n0 + off4];
        const float vv[4] = { v.x, v.y, v.z, v.w };
        #pragma unroll
        for (int e = 0; e < 4; ++e) {
            const unsigned rh = rne_bf16(vv[e]);
            const unsigned rl = rne_bf16(vv[e] - bfbits_to_f(rh));
            th[kr][off4 + e] = (unsigned short)(rh >> 16);
            tl[kr][off4 + e] = (unsigned short)(rl >> 16);
        }
    }
    __syncthreads();
    #pragma unroll
    for (int p = 0; p < 4; ++p) {
        const int nr = p * 16 + sub;
        ushort4 oh, ol;
        oh.x = th[off4 + 0][nr]; oh.y = th[off4 + 1][nr];
        oh.z = th[off4 + 2][nr]; oh.w = th[off4 + 3][nr];
        ol.x = tl[off4 + 0][nr]; ol.y = tl[off4 + 1][nr];
        ol.z = tl[off4 + 2][nr]; ol.w = tl[off4 + 3][nr];
        *(ushort4*)&Wt_hi[(size_t)(n0 + nr) * KD_ + k0 + off4] = oh;
        *(ushort4*)&Wt_lo[(size_t)(n0 + nr) * KD_ + k0 + off4] = ol;
    }
}

// ---------------------------------------------------------------------------
// Kernel 2: cent [64][256] -> centT [256][64] fp32
// ---------------------------------------------------------------------------
__global__ void convert_cent(const float* __restrict__ cent, float* __restrict__ centT) {
    const int k = blockIdx.x;       // 0..63
    const int j = threadIdx.x;      // 0..255
    centT[(size_t)j * KC_ + k] = cent[(size_t)k * NDF_ + j];
}

// ---------------------------------------------------------------------------
// Kernel 3: fused ROI-align + split-bf16 (3-product) MFMA split-K GEMM.
// Tile 32 rois x 256 cols; grid (ks=32, mi=32) = 1024 blocks; 3 blocks/CU.
// KEY CHANGE (R6): the 3.1 KB channel plane is DMA'd into LDS once per
// channel (196 coalesced 16B lane-requests) and the bilinear A-gen reads
// LDS instead of issuing 2048 scalar global gathers per channel-block.
// A-buffer holds a full channel (32 x 64); regenerated every 2 K-steps.
// Per-thread sampling params (one (roi,by) row of 8 bins) are kernel-
// lifetime register constants.
// ---------------------------------------------------------------------------
__global__ __launch_bounds__(256, 3)
void gemm_fused(const float* __restrict__ z_vis, const unsigned short* __restrict__ Wt_hi,
                const unsigned short* __restrict__ Wt_lo, const float* __restrict__ bboxs,
                float* __restrict__ part) {
    __shared__ short Ah[MT_ * APAD_];        // 4.5 KB  [roi][k 0..63] (pad 8)
    __shared__ short Al[MT_ * APAD_];        // 4.5 KB
    __shared__ unsigned short Bh[256 * 32];  // 16 KB   [n][k]
    __shared__ unsigned short Bl[256 * 32];  // 16 KB
    __shared__ float Pl[PLANE_];             // 3136 B  current channel plane

    const int t = threadIdx.x;
    const int ks = blockIdx.x, mi = blockIdx.y;
    const int lane = t & 63, wid = t >> 6;
    const int kbase = ks * KCH_;

    // ---- A-gen assignment: roi row m = t>>3, bin-row by = t&7 ----
    const int m = t >> 3, by = t & 7;
    const int roi = mi * MT_ + m;
    const int bn = mi >> 1;                  // 32 rois per block share one bn

    // kernel-lifetime sampling constants (roi + by fixed per thread)
    int xi0[8], xi1[8];
    float xw0[8], xw1[8];
    int yr0, yr1;
    float wy0v, wy1v;
    {
        const float bx1 = bboxs[roi * 4 + 0], by1 = bboxs[roi * 4 + 1];
        const float bx2 = bboxs[roi * 4 + 2], by2 = bboxs[roi * 4 + 3];
        const float sx = 28.0f / 1920.0f, sy = 28.0f / 1080.0f;
        const float lo_x = bx1 * sx - 0.5f;
        const float binw_x = (bx2 * sx - 0.5f - lo_x) * 0.125f;
        const float lo_y = by1 * sy - 0.5f;
        const float binw_y = (by2 * sy - 0.5f - lo_y) * 0.125f;
        #pragma unroll
        for (int b = 0; b < 8; ++b) {
            const float pos = lo_x + ((float)b + 0.5f) * binw_x;
            const float vx = (pos > -1.0f && pos < 28.0f) ? 1.0f : 0.0f;
            const float pc = fminf(fmaxf(pos, 0.0f), 27.0f);
            const float p0 = floorf(pc);
            const float lx = pc - p0;
            xi0[b] = (int)p0;
            xi1[b] = min(xi0[b] + 1, 27);
            xw0[b] = vx * (1.0f - lx);
            xw1[b] = vx * lx;
        }
        const float pos = lo_y + ((float)by + 0.5f) * binw_y;
        const float vy = (pos > -1.0f && pos < 28.0f) ? 1.0f : 0.0f;
        const float pc = fminf(fmaxf(pos, 0.0f), 27.0f);
        const float p0 = floorf(pc);
        const float ly = pc - p0;
        const int y0 = (int)p0, y1 = min(y0 + 1, 27);
        yr0 = y0 * FX_; yr1 = y1 * FX_;
        wy0v = vy * (1.0f - ly); wy1v = vy * ly;
    }
    const float* plane = z_vis + (size_t)bn * CT_ + (size_t)(T_ - 1) * PLANE_;

    const int brow_l = lane >> 2;            // B-staging lane->row-in-chunk
    const int bkoff = (lane & 3) * 8;        // B-staging lane->k offset (elems)

    // ---- plane DMA: wave 0, 3 full + one 4-lane 16B instruction = 3136 B ----
    auto plane_load = [&](int cc) {
        if (wid != 0) return;
        const char* gb = (const char*)(plane + (size_t)(ks * NCH_ + cc) * CHSTRIDE_);
        #pragma unroll
        for (int i = 0; i < 3; ++i)
            __builtin_amdgcn_global_load_lds(
                (const __attribute__((address_space(1))) void*)(gb + (i * 64 + lane) * 16),
                (__attribute__((address_space(3))) void*)((char*)Pl + i * 1024), 16, 0, 0);
        if (lane < 4)
            __builtin_amdgcn_global_load_lds(
                (const __attribute__((address_space(1))) void*)(gb + (192 + lane) * 16),
                (__attribute__((address_space(3))) void*)((char*)Pl + 3072), 16, 0, 0);
    };

    auto stage_B = [&](int s) {              // s = K-step within split (0..29)
        #pragma unroll
        for (int qq = 0; qq < 4; ++qq) {
            const int rbase = qq * 64 + wid * 16;           // wave-uniform
            const size_t goff = (size_t)(rbase + brow_l) * KD_ + kbase + s * 32 + bkoff;
            __builtin_amdgcn_global_load_lds(
                (const __attribute__((address_space(1))) void*)(Wt_hi + goff),
                (__attribute__((address_space(3))) void*)&Bh[rbase * 32], 16, 0, 0);
            __builtin_amdgcn_global_load_lds(
                (const __attribute__((address_space(1))) void*)(Wt_lo + goff),
                (__attribute__((address_space(3))) void*)&Bl[rbase * 32], 16, 0, 0);
        }
    };

    // ---- A-gen: full channel from LDS plane; 8 bins for (m, by) ----
    auto stage_A = [&]() {
        unsigned rh[8], rl[8];
        #pragma unroll
        for (int b = 0; b < 8; ++b) {
            const float v00 = Pl[yr0 + xi0[b]], v01 = Pl[yr0 + xi1[b]];
            const float v10 = Pl[yr1 + xi0[b]], v11 = Pl[yr1 + xi1[b]];
            const float val = wy0v * (xw0[b] * v00 + xw1[b] * v01)
                            + wy1v * (xw0[b] * v10 + xw1[b] * v11);
            rh[b] = rne_bf16(val);
            rl[b] = rne_bf16(val - bfbits_to_f(rh[b]));
        }
        const uint4 hh = make_uint4(__builtin_amdgcn_perm(rh[1], rh[0], 0x07060302u),
                                    __builtin_amdgcn_perm(rh[3], rh[2], 0x07060302u),
                                    __builtin_amdgcn_perm(rh[5], rh[4], 0x07060302u),
                                    __builtin_amdgcn_perm(rh[7], rh[6], 0x07060302u));
        const uint4 ll = make_uint4(__builtin_amdgcn_perm(rl[1], rl[0], 0x07060302u),
                                    __builtin_amdgcn_perm(rl[3], rl[2], 0x07060302u),
                                    __builtin_amdgcn_perm(rl[5], rl[4], 0x07060302u),
                                    __builtin_amdgcn_perm(rl[7], rl[6], 0x07060302u));
        *(uint4*)&Ah[m * APAD_ + by * 8] = hh;   // k-local = by*8 + bx
        *(uint4*)&Al[m * APAD_ + by * 8] = ll;
    };

    const int fr = lane & 15, fq = lane >> 4;
    f32x4 acc[2][4] = {};

    // ---- prologue: plane(0) + B(0) in flight; A-gen(0) after drain ----
    plane_load(0);
    stage_B(0);
    __syncthreads();                         // vmcnt drain: plane(0)+B(0) landed
    stage_A();                               // A(ch 0) -> LDS

    for (int cc = 0; cc < NCH_; ++cc) {
        #pragma unroll
        for (int half = 0; half < 2; ++half) {
            const int s = 2 * cc + half;
            __syncthreads();                 // A written / B(s)(+plane) landed

            bf16x8 afh[2], afl[2], bh[4], bl[4];
            #pragma unroll
            for (int i = 0; i < 2; ++i) {
                afh[i] = *(const bf16x8*)&Ah[(i * 16 + fr) * APAD_ + half * 32 + fq * 8];
                afl[i] = *(const bf16x8*)&Al[(i * 16 + fr) * APAD_ + half * 32 + fq * 8];
            }
            #pragma unroll
            for (int j = 0; j < 4; ++j) {
                bh[j] = *(const bf16x8*)&Bh[(wid * 64 + j * 16 + fr) * 32 + fq * 8];
                bl[j] = *(const bf16x8*)&Bl[(wid * 64 + j * 16 + fr) * 32 + fq * 8];
            }
            __syncthreads();                 // reads done; LDS reusable

            if (half == 0) {
                stage_B(s + 1);
                if (cc + 1 < NCH_) plane_load(cc + 1);   // next plane in flight
            } else if (cc + 1 < NCH_) {
                stage_B(s + 1);
                stage_A();                   // A(ch cc+1); plane landed at sync above
            }

            #pragma unroll
            for (int j = 0; j < 4; ++j)
                #pragma unroll
                for (int i = 0; i < 2; ++i) {
                    acc[i][j] = __builtin_amdgcn_mfma_f32_16x16x32_bf16(afh[i], bh[j], acc[i][j], 0, 0, 0);
                    acc[i][j] = __builtin_amdgcn_mfma_f32_16x16x32_bf16(afl[i], bh[j], acc[i][j], 0, 0, 0);
                    acc[i][j] = __builtin_amdgcn_mfma_f32_16x16x32_bf16(afh[i], bl[j], acc[i][j], 0, 0, 0);
                }
        }
    }

    // ---- write split partial; C/D: col=lane&15, row=(lane>>4)*4+r ----
    float* pb = part + (size_t)ks * M_ * NDF_;
    #pragma unroll
    for (int i = 0; i < 2; ++i) {
        const int row = mi * MT_ + i * 16 + fq * 4;
        #pragma unroll
        for (int j = 0; j < 4; ++j) {
            const int col = wid * 64 + j * 16 + fr;
            #pragma unroll
            for (int r = 0; r < 4; ++r)
                pb[(size_t)(row + r) * NDF_ + col] = acc[i][j][r];
        }
    }
}

// ---------------------------------------------------------------------------
// Kernel 4: reduce split-K + spatial term + soft-assignment clustering.
// ---------------------------------------------------------------------------
__global__ __launch_bounds__(256)
void cluster_kernel(const float* __restrict__ part, const float* __restrict__ bboxs,
                    const float* __restrict__ b_vis, const float* __restrict__ W_spc,
                    const float* __restrict__ b_spc, const float* __restrict__ centT,
                    float* __restrict__ out) {
    const int row = blockIdx.x, t = threadIdx.x;
    __shared__ float zs[NDF_];
    __shared__ float dp[4][KC_];

    float a = 0.0f;
    #pragma unroll
    for (int kp = 0; kp < KS_; ++kp)
        a += part[(size_t)kp * M_ * NDF_ + (size_t)row * NDF_ + t];

    const float x1 = bboxs[row * 4 + 0], y1 = bboxs[row * 4 + 1];
    const float x2 = bboxs[row * 4 + 2], y2 = bboxs[row * 4 + 3];
    const float cx = x1 + (x2 - x1) * 0.5f - 960.0f;
    const float cy = y1 + (y2 - y1) * 0.5f - 540.0f;
    const float nrm = sqrtf(cx * cx + cy * cy) / sqrtf(960.0f * 960.0f + 540.0f * 540.0f);

    const float zj = a + b_vis[t] + nrm * W_spc[t] + b_spc[t];
    zs[t] = zj;
    out[(size_t)row * NDF_ + t] = zj;                         // output 0: z
    __syncthreads();

    const int k = t & 63, qq = t >> 6;
    {
        float d2 = 0.0f;
        const float* ct = centT + (size_t)qq * 64 * KC_;
        #pragma unroll 8
        for (int j = 0; j < 64; ++j) {
            const float df = zs[qq * 64 + j] - ct[(size_t)j * KC_ + k];
            d2 += df * df;
        }
        dp[qq][k] = d2;
    }
    __syncthreads();

    if (t < 64) {
        const float d = sqrtf(dp[0][t] + dp[1][t] + dp[2][t] + dp[3][t]);
        const float su = 1.0f / (1.0f + d);                   // ALPHA=1
        float sum = su;
        #pragma unroll
        for (int mk = 1; mk < 64; mk <<= 1) sum += __shfl_xor(sum, mk, 64);
        out[(size_t)M_ * NDF_ + (size_t)row * KC_ + t] = su / sum;   // output 1: s
        float v = d; int idx = t;
        #pragma unroll
        for (int mk = 1; mk < 64; mk <<= 1) {
            const float ov = __shfl_xor(v, mk, 64);
            const int oi = __shfl_xor(idx, mk, 64);
            if (ov < v || (ov == v && oi < idx)) { v = ov; idx = oi; }
        }
        if (t == 0)
            out[(size_t)M_ * NDF_ + (size_t)M_ * KC_ + row] = (float)idx;  // output 2: c
    }
}

// ---------------------------------------------------------------------------
extern "C" void kernel_launch(void* const* d_in, const int* in_sizes, int n_in,
                              void* d_out, int out_size, void* d_ws, size_t ws_size,
                              hipStream_t stream) {
    const float* z_vis = (const float*)d_in[0];
    const float* bboxs = (const float*)d_in[1];
    const float* W_vis = (const float*)d_in[2];
    const float* b_vis = (const float*)d_in[3];
    const float* W_spc = (const float*)d_in[4];
    const float* b_spc = (const float*)d_in[5];
    const float* cent  = (const float*)d_in[6];
    float* out = (float*)d_out;

    char* ws = (char*)d_ws;
    unsigned short* Wt_hi = (unsigned short*)ws;                          // 15,728,640 B
    unsigned short* Wt_lo = (unsigned short*)(ws + 15728640);             // 15,728,640 B
    float*          centT = (float*)(ws + 2 * 15728640);                  //     65,536 B
    float*          part  = (float*)(ws + 2 * 15728640 + 65536);          // 33,554,432 B

    convert_w<<<dim3(KD_ / 64, NDF_ / 64), 256, 0, stream>>>(W_vis, Wt_hi, Wt_lo);
    convert_cent<<<KC_, 256, 0, stream>>>(cent, centT);
    gemm_fused<<<dim3(KS_, M_ / MT_), 256, 0, stream>>>(z_vis, Wt_hi, Wt_lo, bboxs, part);
    cluster_kernel<<<M_, 256, 0, stream>>>(part, bboxs, b_vis, W_spc, b_spc, centT, out);
}

// Round 7
// 370.416 us; speedup vs baseline: 1.5089x; 1.1023x over previous
//
#include <hip/hip_runtime.h>
#include <cstdint>
#include <cstddef>

// ---- problem constants ----
#define BN_   16
#define C_    480
#define T_    8
#define FY_   28
#define FX_   28
#define NDF_  256
#define KC_   64
#define M_    1024            // BN*SN rows
#define KD_   30720           // C*8*8
#define PLANE_ 784
#define CHSTRIDE_ (T_*PLANE_) // 6272 floats between channels
#define CT_   (C_*CHSTRIDE_)  // per-bn stride
#define KS_   32              // split-K factor
#define KCH_  960             // K per split (15 whole channels)
#define NCH_  15              // channels per split
#define NSTEP_ 30             // K-steps per split (BK=32)
#define MT_   32              // M-tile (rois per block)
#define APAD_ 72              // A LDS row stride (ushorts): 64 + 8 pad
#define BTILE_ 16384          // ushorts per packed step-tile (hi 8192 + lo 8192)

typedef __attribute__((ext_vector_type(8))) short bf16x8;
typedef __attribute__((ext_vector_type(4))) float f32x4;

__device__ __forceinline__ unsigned rne_bf16(float f) {
    union { float f; unsigned u; } v; v.f = f;
    return v.u + 0x7FFFu + ((v.u >> 16) & 1u);   // RNE; bf16 bits = result >> 16
}
__device__ __forceinline__ float bfbits_to_f(unsigned r) {
    union { unsigned u; float f; } v; v.u = r & 0xFFFF0000u;
    return v.f;
}

// ---------------------------------------------------------------------------
// Kernel 1: pack W [30720][256] fp32 into per-step contiguous bf16 tiles:
// Bpack[ks*30+s] = [hi: n(256) x k(32)][lo: n(256) x k(32)]  (k contiguous).
// The tile layout is byte-identical to the GEMM's LDS destination, so the
// per-step DMA reads one fully-sequential 32 KB stream (R6 read 512 scattered
// 64B segments per step with 61 KB stride -> 0.68 TB/s effective; this fixes it).
// One block per step-tile; reads coalesced, writes 64 B/lane contiguous.
// ---------------------------------------------------------------------------
__global__ __launch_bounds__(256)
void convert_pack(const float* __restrict__ W, unsigned short* __restrict__ Bpack) {
    const int blk = blockIdx.x;              // 0..959 = ks*30 + s
    const int kb = blk * 32;                 // global k base (ks*960 + s*32)
    const int n = threadIdx.x;               // output column
    unsigned hw[16], lw[16];
    #pragma unroll
    for (int p = 0; p < 16; ++p) {           // k-pairs 2p, 2p+1
        const float v0 = W[(size_t)(kb + 2 * p) * NDF_ + n];
        const float v1 = W[(size_t)(kb + 2 * p + 1) * NDF_ + n];
        const unsigned h0 = rne_bf16(v0), h1 = rne_bf16(v1);
        const unsigned l0 = rne_bf16(v0 - bfbits_to_f(h0));
        const unsigned l1 = rne_bf16(v1 - bfbits_to_f(h1));
        hw[p] = __builtin_amdgcn_perm(h1, h0, 0x07060302u);  // low16=k even
        lw[p] = __builtin_amdgcn_perm(l1, l0, 0x07060302u);
    }
    unsigned short* hb = Bpack + (size_t)blk * BTILE_;       // hi tile
    unsigned short* lb = hb + 8192;                          // lo tile
    uint4* ho = (uint4*)hb + n * 4;          // row n = ushorts [n*32, n*32+32)
    uint4* lo = (uint4*)lb + n * 4;
    #pragma unroll
    for (int q = 0; q < 4; ++q) {
        ho[q] = make_uint4(hw[q * 4 + 0], hw[q * 4 + 1], hw[q * 4 + 2], hw[q * 4 + 3]);
        lo[q] = make_uint4(lw[q * 4 + 0], lw[q * 4 + 1], lw[q * 4 + 2], lw[q * 4 + 3]);
    }
}

// ---------------------------------------------------------------------------
// Kernel 2: cent [64][256] -> centT [256][64] fp32
// ---------------------------------------------------------------------------
__global__ void convert_cent(const float* __restrict__ cent, float* __restrict__ centT) {
    const int k = blockIdx.x;       // 0..63
    const int j = threadIdx.x;      // 0..255
    centT[(size_t)j * KC_ + k] = cent[(size_t)k * NDF_ + j];
}

// ---------------------------------------------------------------------------
// Kernel 3: fused ROI-align + split-bf16 (3-product) MFMA split-K GEMM.
// Tile 32 rois x 256 cols; grid (ks=32, mi=32) = 1024 blocks; 3 blocks/CU.
// R7: B staged from the packed contiguous tiles; split results accumulated
// with fp32 atomicAdd into z_acc (1 MB) -- removes the 33.5 MB part buffer
// (harness poisons ws every timed iteration, so ws bytes cost wall time).
// ---------------------------------------------------------------------------
__global__ __launch_bounds__(256, 3)
void gemm_fused(const float* __restrict__ z_vis, const unsigned short* __restrict__ Bpack,
                const float* __restrict__ bboxs, float* __restrict__ z_acc) {
    __shared__ short Ah[MT_ * APAD_];        // 4.5 KB  [roi][k 0..63] (pad 8)
    __shared__ short Al[MT_ * APAD_];        // 4.5 KB
    __shared__ unsigned short Bh[256 * 32];  // 16 KB   [n][k]
    __shared__ unsigned short Bl[256 * 32];  // 16 KB
    __shared__ float Pl[PLANE_];             // 3136 B  current channel plane

    const int t = threadIdx.x;
    const int ks = blockIdx.x, mi = blockIdx.y;
    const int lane = t & 63, wid = t >> 6;

    // ---- A-gen assignment: roi row m = t>>3, bin-row by = t&7 ----
    const int m = t >> 3, by = t & 7;
    const int roi = mi * MT_ + m;
    const int bn = mi >> 1;                  // 32 rois per block share one bn

    // kernel-lifetime sampling constants (roi + by fixed per thread)
    int xi0[8], xi1[8];
    float xw0[8], xw1[8];
    int yr0, yr1;
    float wy0v, wy1v;
    {
        const float bx1 = bboxs[roi * 4 + 0], by1 = bboxs[roi * 4 + 1];
        const float bx2 = bboxs[roi * 4 + 2], by2 = bboxs[roi * 4 + 3];
        const float sx = 28.0f / 1920.0f, sy = 28.0f / 1080.0f;
        const float lo_x = bx1 * sx - 0.5f;
        const float binw_x = (bx2 * sx - 0.5f - lo_x) * 0.125f;
        const float lo_y = by1 * sy - 0.5f;
        const float binw_y = (by2 * sy - 0.5f - lo_y) * 0.125f;
        #pragma unroll
        for (int b = 0; b < 8; ++b) {
            const float pos = lo_x + ((float)b + 0.5f) * binw_x;
            const float vx = (pos > -1.0f && pos < 28.0f) ? 1.0f : 0.0f;
            const float pc = fminf(fmaxf(pos, 0.0f), 27.0f);
            const float p0 = floorf(pc);
            const float lx = pc - p0;
            xi0[b] = (int)p0;
            xi1[b] = min(xi0[b] + 1, 27);
            xw0[b] = vx * (1.0f - lx);
            xw1[b] = vx * lx;
        }
        const float pos = lo_y + ((float)by + 0.5f) * binw_y;
        const float vy = (pos > -1.0f && pos < 28.0f) ? 1.0f : 0.0f;
        const float pc = fminf(fmaxf(pos, 0.0f), 27.0f);
        const float p0 = floorf(pc);
        const float ly = pc - p0;
        const int y0 = (int)p0, y1 = min(y0 + 1, 27);
        yr0 = y0 * FX_; yr1 = y1 * FX_;
        wy0v = vy * (1.0f - ly); wy1v = vy * ly;
    }
    const float* plane = z_vis + (size_t)bn * CT_ + (size_t)(T_ - 1) * PLANE_;

    // ---- plane DMA: wave 0, 3 full + one 4-lane 16B instruction = 3136 B ----
    auto plane_load = [&](int cc) {
        if (wid != 0) return;
        const char* gb = (const char*)(plane + (size_t)(ks * NCH_ + cc) * CHSTRIDE_);
        #pragma unroll
        for (int i = 0; i < 3; ++i)
            __builtin_amdgcn_global_load_lds(
                (const __attribute__((address_space(1))) void*)(gb + (i * 64 + lane) * 16),
                (__attribute__((address_space(3))) void*)((char*)Pl + i * 1024), 16, 0, 0);
        if (lane < 4)
            __builtin_amdgcn_global_load_lds(
                (const __attribute__((address_space(1))) void*)(gb + (192 + lane) * 16),
                (__attribute__((address_space(3))) void*)((char*)Pl + 3072), 16, 0, 0);
    };

    // ---- B staging: packed tile; global source == LDS layout, lane*16B ----
    auto stage_B = [&](int s) {
        const unsigned short* hb = Bpack + (size_t)(ks * NSTEP_ + s) * BTILE_;
        #pragma unroll
        for (int qq = 0; qq < 4; ++qq) {
            const int off = (qq * 64 + wid * 16) * 32;      // wave-uniform ushort offset
            __builtin_amdgcn_global_load_lds(
                (const __attribute__((address_space(1))) void*)(hb + off + lane * 8),
                (__attribute__((address_space(3))) void*)&Bh[off], 16, 0, 0);
            __builtin_amdgcn_global_load_lds(
                (const __attribute__((address_space(1))) void*)(hb + 8192 + off + lane * 8),
                (__attribute__((address_space(3))) void*)&Bl[off], 16, 0, 0);
        }
    };

    // ---- A-gen: full channel from LDS plane; 8 bins for (m, by) ----
    auto stage_A = [&]() {
        unsigned rh[8], rl[8];
        #pragma unroll
        for (int b = 0; b < 8; ++b) {
            const float v00 = Pl[yr0 + xi0[b]], v01 = Pl[yr0 + xi1[b]];
            const float v10 = Pl[yr1 + xi0[b]], v11 = Pl[yr1 + xi1[b]];
            const float val = wy0v * (xw0[b] * v00 + xw1[b] * v01)
                            + wy1v * (xw0[b] * v10 + xw1[b] * v11);
            rh[b] = rne_bf16(val);
            rl[b] = rne_bf16(val - bfbits_to_f(rh[b]));
        }
        const uint4 hh = make_uint4(__builtin_amdgcn_perm(rh[1], rh[0], 0x07060302u),
                                    __builtin_amdgcn_perm(rh[3], rh[2], 0x07060302u),
                                    __builtin_amdgcn_perm(rh[5], rh[4], 0x07060302u),
                                    __builtin_amdgcn_perm(rh[7], rh[6], 0x07060302u));
        const uint4 ll = make_uint4(__builtin_amdgcn_perm(rl[1], rl[0], 0x07060302u),
                                    __builtin_amdgcn_perm(rl[3], rl[2], 0x07060302u),
                                    __builtin_amdgcn_perm(rl[5], rl[4], 0x07060302u),
                                    __builtin_amdgcn_perm(rl[7], rl[6], 0x07060302u));
        *(uint4*)&Ah[m * APAD_ + by * 8] = hh;   // k-local = by*8 + bx
        *(uint4*)&Al[m * APAD_ + by * 8] = ll;
    };

    const int fr = lane & 15, fq = lane >> 4;
    f32x4 acc[2][4] = {};

    // ---- prologue: plane(0) + B(0) in flight; A-gen(0) after drain ----
    plane_load(0);
    stage_B(0);
    __syncthreads();                         // vmcnt drain: plane(0)+B(0) landed
    stage_A();                               // A(ch 0) -> LDS

    for (int cc = 0; cc < NCH_; ++cc) {
        #pragma unroll
        for (int half = 0; half < 2; ++half) {
            const int s = 2 * cc + half;
            __syncthreads();                 // A written / B(s)(+plane) landed

            bf16x8 afh[2], afl[2], bh[4], bl[4];
            #pragma unroll
            for (int i = 0; i < 2; ++i) {
                afh[i] = *(const bf16x8*)&Ah[(i * 16 + fr) * APAD_ + half * 32 + fq * 8];
                afl[i] = *(const bf16x8*)&Al[(i * 16 + fr) * APAD_ + half * 32 + fq * 8];
            }
            #pragma unroll
            for (int j = 0; j < 4; ++j) {
                bh[j] = *(const bf16x8*)&Bh[(wid * 64 + j * 16 + fr) * 32 + fq * 8];
                bl[j] = *(const bf16x8*)&Bl[(wid * 64 + j * 16 + fr) * 32 + fq * 8];
            }
            __syncthreads();                 // reads done; LDS reusable

            if (half == 0) {
                stage_B(s + 1);
                if (cc + 1 < NCH_) plane_load(cc + 1);   // next plane in flight
            } else if (cc + 1 < NCH_) {
                stage_B(s + 1);
                stage_A();                   // A(ch cc+1); plane landed at sync above
            }

            #pragma unroll
            for (int j = 0; j < 4; ++j)
                #pragma unroll
                for (int i = 0; i < 2; ++i) {
                    acc[i][j] = __builtin_amdgcn_mfma_f32_16x16x32_bf16(afh[i], bh[j], acc[i][j], 0, 0, 0);
                    acc[i][j] = __builtin_amdgcn_mfma_f32_16x16x32_bf16(afl[i], bh[j], acc[i][j], 0, 0, 0);
                    acc[i][j] = __builtin_amdgcn_mfma_f32_16x16x32_bf16(afh[i], bl[j], acc[i][j], 0, 0, 0);
                }
        }
    }

    // ---- accumulate split partial into z_acc (device-scope fp32 atomics) ----
    #pragma unroll
    for (int i = 0; i < 2; ++i) {
        const int row = mi * MT_ + i * 16 + fq * 4;
        #pragma unroll
        for (int j = 0; j < 4; ++j) {
            const int col = wid * 64 + j * 16 + fr;
            #pragma unroll
            for (int r = 0; r < 4; ++r)
                atomicAdd(&z_acc[(size_t)(row + r) * NDF_ + col], acc[i][j][r]);
        }
    }
}

// ---------------------------------------------------------------------------
// Kernel 4: spatial term + soft-assignment clustering (z_acc already reduced).
// ---------------------------------------------------------------------------
__global__ __launch_bounds__(256)
void cluster_kernel(const float* __restrict__ z_acc, const float* __restrict__ bboxs,
                    const float* __restrict__ b_vis, const float* __restrict__ W_spc,
                    const float* __restrict__ b_spc, const float* __restrict__ centT,
                    float* __restrict__ out) {
    const int row = blockIdx.x, t = threadIdx.x;
    __shared__ float zs[NDF_];
    __shared__ float dp[4][KC_];

    const float a = z_acc[(size_t)row * NDF_ + t];

    const float x1 = bboxs[row * 4 + 0], y1 = bboxs[row * 4 + 1];
    const float x2 = bboxs[row * 4 + 2], y2 = bboxs[row * 4 + 3];
    const float cx = x1 + (x2 - x1) * 0.5f - 960.0f;
    const float cy = y1 + (y2 - y1) * 0.5f - 540.0f;
    const float nrm = sqrtf(cx * cx + cy * cy) / sqrtf(960.0f * 960.0f + 540.0f * 540.0f);

    const float zj = a + b_vis[t] + nrm * W_spc[t] + b_spc[t];
    zs[t] = zj;
    out[(size_t)row * NDF_ + t] = zj;                         // output 0: z
    __syncthreads();

    const int k = t & 63, qq = t >> 6;
    {
        float d2 = 0.0f;
        const float* ct = centT + (size_t)qq * 64 * KC_;
        #pragma unroll 8
        for (int j = 0; j < 64; ++j) {
            const float df = zs[qq * 64 + j] - ct[(size_t)j * KC_ + k];
            d2 += df * df;
        }
        dp[qq][k] = d2;
    }
    __syncthreads();

    if (t < 64) {
        const float d = sqrtf(dp[0][t] + dp[1][t] + dp[2][t] + dp[3][t]);
        const float su = 1.0f / (1.0f + d);                   // ALPHA=1
        float sum = su;
        #pragma unroll
        for (int mk = 1; mk < 64; mk <<= 1) sum += __shfl_xor(sum, mk, 64);
        out[(size_t)M_ * NDF_ + (size_t)row * KC_ + t] = su / sum;   // output 1: s
        float v = d; int idx = t;
        #pragma unroll
        for (int mk = 1; mk < 64; mk <<= 1) {
            const float ov = __shfl_xor(v, mk, 64);
            const int oi = __shfl_xor(idx, mk, 64);
            if (ov < v || (ov == v && oi < idx)) { v = ov; idx = oi; }
        }
        if (t == 0)
            out[(size_t)M_ * NDF_ + (size_t)M_ * KC_ + row] = (float)idx;  // output 2: c
    }
}

// ---------------------------------------------------------------------------
extern "C" void kernel_launch(void* const* d_in, const int* in_sizes, int n_in,
                              void* d_out, int out_size, void* d_ws, size_t ws_size,
                              hipStream_t stream) {
    const float* z_vis = (const float*)d_in[0];
    const float* bboxs = (const float*)d_in[1];
    const float* W_vis = (const float*)d_in[2];
    const float* b_vis = (const float*)d_in[3];
    const float* W_spc = (const float*)d_in[4];
    const float* b_spc = (const float*)d_in[5];
    const float* cent  = (const float*)d_in[6];
    float* out = (float*)d_out;

    char* ws = (char*)d_ws;
    unsigned short* Bpack = (unsigned short*)ws;                 // 960*32768 = 31,457,280 B
    float*          centT = (float*)(ws + 31457280);             //     65,536 B
    float*          z_acc = (float*)(ws + 31457280 + 65536);     //  1,048,576 B
    // total ws: ~32.6 MB (was 65 MB; harness poisons ws every timed iter).

    convert_pack<<<KS_ * NSTEP_, 256, 0, stream>>>(W_vis, Bpack);
    convert_cent<<<KC_, 256, 0, stream>>>(cent, centT);
    hipMemsetAsync(z_acc, 0, (size_t)M_ * NDF_ * sizeof(float), stream);
    gemm_fused<<<dim3(KS_, M_ / MT_), 256, 0, stream>>>(z_vis, Bpack, bboxs, z_acc);
    cluster_kernel<<<M_, 256, 0, stream>>>(z_acc, bboxs, b_vis, W_spc, b_spc, centT, out);
}

// Round 8
// 346.911 us; speedup vs baseline: 1.6111x; 1.0678x over previous
//
#include <hip/hip_runtime.h>
#include <cstdint>
#include <cstddef>

// ---- problem constants ----
#define BN_   16
#define C_    480
#define T_    8
#define FY_   28
#define FX_   28
#define NDF_  256
#define KC_   64
#define M_    1024            // BN*SN rows
#define KD_   30720           // C*8*8
#define PLANE_ 784
#define CHSTRIDE_ (T_*PLANE_) // 6272 floats between channels
#define CT_   (C_*CHSTRIDE_)  // per-bn stride
#define KS_   32              // split-K factor
#define KCH_  960             // K per split (15 whole channels)
#define NCH_  15              // channels per split
#define NSTEP_ 30             // K-steps per split (BK=32)
#define MT_   64              // M-tile (rois per block) -- one full bn image
#define AOS_  520             // A LDS octet stride in ushorts (1040 B; %32 words = 4 -> bank rotate)
#define BTILE_ 16384          // ushorts per packed step-tile (hi 8192 + lo 8192)

typedef __attribute__((ext_vector_type(8))) short bf16x8;
typedef __attribute__((ext_vector_type(4))) float f32x4;

__device__ __forceinline__ unsigned rne_bf16(float f) {
    union { float f; unsigned u; } v; v.f = f;
    return v.u + 0x7FFFu + ((v.u >> 16) & 1u);   // RNE; bf16 bits = result >> 16
}
__device__ __forceinline__ float bfbits_to_f(unsigned r) {
    union { unsigned u; float f; } v; v.u = r & 0xFFFF0000u;
    return v.f;
}
__device__ __forceinline__ void lds_dma16(const void* g, void* l) {
    __builtin_amdgcn_global_load_lds((const __attribute__((address_space(1))) void*)g,
                                     (__attribute__((address_space(3))) void*)l, 16, 0, 0);
}

// ---------------------------------------------------------------------------
// Kernel 1: pack W into per-step tiles in CONFLICT-FREE octet-major layout:
// tile(ks*30+s) = hi[oct(4)][n(256)][8 ushorts] ++ lo[same].
// element (n,k): hi[(k>>3)*2048 + n*8 + (k&7)].  Reads & writes coalesced.
// ---------------------------------------------------------------------------
__global__ __launch_bounds__(256)
void convert_pack(const float* __restrict__ W, unsigned short* __restrict__ Bpack) {
    const int blk = blockIdx.x;              // 0..959 = ks*30 + s
    const int kb = blk * 32;                 // global k base
    const int n = threadIdx.x;
    unsigned hw[16], lw[16];
    #pragma unroll
    for (int p = 0; p < 16; ++p) {           // k-pair (2p, 2p+1)
        const float v0 = W[(size_t)(kb + 2 * p) * NDF_ + n];
        const float v1 = W[(size_t)(kb + 2 * p + 1) * NDF_ + n];
        const unsigned h0 = rne_bf16(v0), h1 = rne_bf16(v1);
        const unsigned l0 = rne_bf16(v0 - bfbits_to_f(h0));
        const unsigned l1 = rne_bf16(v1 - bfbits_to_f(h1));
        hw[p] = __builtin_amdgcn_perm(h1, h0, 0x07060302u);  // lo16 = even k
        lw[p] = __builtin_amdgcn_perm(l1, l0, 0x07060302u);
    }
    uint4* hb4 = (uint4*)(Bpack + (size_t)blk * BTILE_);     // hi: 1024 uint4
    uint4* lb4 = hb4 + 1024;                                 // lo
    #pragma unroll
    for (int o = 0; o < 4; ++o) {            // octet o = k 8o..8o+7 -> uint4 idx o*256+n
        hb4[o * 256 + n] = make_uint4(hw[o * 4 + 0], hw[o * 4 + 1], hw[o * 4 + 2], hw[o * 4 + 3]);
        lb4[o * 256 + n] = make_uint4(lw[o * 4 + 0], lw[o * 4 + 1], lw[o * 4 + 2], lw[o * 4 + 3]);
    }
}

// ---------------------------------------------------------------------------
// Kernel 2: cent [64][256] -> centT [256][64] fp32
// ---------------------------------------------------------------------------
__global__ void convert_cent(const float* __restrict__ cent, float* __restrict__ centT) {
    const int k = blockIdx.x;
    const int j = threadIdx.x;
    centT[(size_t)j * KC_ + k] = cent[(size_t)k * NDF_ + j];
}

// ---------------------------------------------------------------------------
// Kernel 3: fused ROI-align + split-bf16 (3-product) MFMA split-K GEMM.
// R8: M-tile 64 (one bn image/block), grid (ks=32, mi=16) = 512 blocks;
// 48 MFMA per step vs the same 32 KB B-DMA (2x arithmetic intensity, half
// the barriers); conflict-free octet-major LDS layouts for A and B.
// ---------------------------------------------------------------------------
__global__ __launch_bounds__(256, 2)
void gemm_fused(const float* __restrict__ z_vis, const unsigned short* __restrict__ Bpack,
                const float* __restrict__ bboxs, float* __restrict__ z_acc) {
    __shared__ short Ah[8 * AOS_];           // 8.3 KB  [oct][m][8]
    __shared__ short Al[8 * AOS_];           // 8.3 KB
    __shared__ unsigned short Bh[8192];      // 16 KB   [oct(4)][n(256)][8]
    __shared__ unsigned short Bl[8192];      // 16 KB
    __shared__ float Pl[PLANE_];             // 3.1 KB  current channel plane

    const int t = threadIdx.x;
    const int ks = blockIdx.x, mi = blockIdx.y;   // mi == bn
    const int lane = t & 63, wid = t >> 6;

    // ---- A-gen assignment: m = t>>2 (0..63); by-pair {t&3, (t&3)+4} ----
    const int m = t >> 2, byl = t & 3;
    const int roi = mi * MT_ + m;

    // kernel-lifetime sampling constants
    int xi0[8], xi1[8];
    float xw0[8], xw1[8];
    int yr0[2], yr1[2];
    float wy0[2], wy1[2];
    {
        const float bx1 = bboxs[roi * 4 + 0], by1 = bboxs[roi * 4 + 1];
        const float bx2 = bboxs[roi * 4 + 2], by2 = bboxs[roi * 4 + 3];
        const float sx = 28.0f / 1920.0f, sy = 28.0f / 1080.0f;
        const float lo_x = bx1 * sx - 0.5f;
        const float binw_x = (bx2 * sx - 0.5f - lo_x) * 0.125f;
        const float lo_y = by1 * sy - 0.5f;
        const float binw_y = (by2 * sy - 0.5f - lo_y) * 0.125f;
        #pragma unroll
        for (int b = 0; b < 8; ++b) {
            const float pos = lo_x + ((float)b + 0.5f) * binw_x;
            const float vx = (pos > -1.0f && pos < 28.0f) ? 1.0f : 0.0f;
            const float pc = fminf(fmaxf(pos, 0.0f), 27.0f);
            const float p0 = floorf(pc);
            const float lx = pc - p0;
            xi0[b] = (int)p0;
            xi1[b] = min(xi0[b] + 1, 27);
            xw0[b] = vx * (1.0f - lx);
            xw1[b] = vx * lx;
        }
        #pragma unroll
        for (int h = 0; h < 2; ++h) {
            const int by = byl + h * 4;
            const float pos = lo_y + ((float)by + 0.5f) * binw_y;
            const float vy = (pos > -1.0f && pos < 28.0f) ? 1.0f : 0.0f;
            const float pc = fminf(fmaxf(pos, 0.0f), 27.0f);
            const float p0 = floorf(pc);
            const float ly = pc - p0;
            const int y0 = (int)p0, y1 = min(y0 + 1, 27);
            yr0[h] = y0 * FX_; yr1[h] = y1 * FX_;
            wy0[h] = vy * (1.0f - ly); wy1[h] = vy * ly;
        }
    }
    const float* plane = z_vis + (size_t)mi * CT_ + (size_t)(T_ - 1) * PLANE_;

    // ---- plane DMA: 4 waves cover 3136 B (wave3: 4 lanes) ----
    auto plane_load = [&](int cc) {
        const char* gb = (const char*)(plane + (size_t)(ks * NCH_ + cc) * CHSTRIDE_);
        if (wid < 3) {
            lds_dma16(gb + (wid * 64 + lane) * 16, (char*)Pl + wid * 1024);
        } else if (lane < 4) {
            lds_dma16(gb + (192 + lane) * 16, (char*)Pl + 3072);
        }
    };

    // ---- B staging: contiguous 16 KB hi + 16 KB lo; layout == LDS ----
    auto stage_B = [&](int s) {
        const char* hb = (const char*)(Bpack + (size_t)(ks * NSTEP_ + s) * BTILE_);
        #pragma unroll
        for (int qq = 0; qq < 4; ++qq) {
            const int chunk = (qq * 4 + wid) * 1024;        // wave-uniform byte offset
            lds_dma16(hb + chunk + lane * 16, (char*)Bh + chunk);
            lds_dma16(hb + 16384 + chunk + lane * 16, (char*)Bl + chunk);
        }
    };

    // ---- A-gen: one channel (64 k) from LDS plane; 2 octets per thread ----
    auto stage_A = [&]() {
        #pragma unroll
        for (int h = 0; h < 2; ++h) {
            const int by = byl + h * 4;                     // octet index
            const int r0 = yr0[h], r1 = yr1[h];
            const float w0 = wy0[h], w1 = wy1[h];
            unsigned rh[8], rl[8];
            #pragma unroll
            for (int b = 0; b < 8; ++b) {
                const float v00 = Pl[r0 + xi0[b]], v01 = Pl[r0 + xi1[b]];
                const float v10 = Pl[r1 + xi0[b]], v11 = Pl[r1 + xi1[b]];
                const float val = w0 * (xw0[b] * v00 + xw1[b] * v01)
                                + w1 * (xw0[b] * v10 + xw1[b] * v11);
                rh[b] = rne_bf16(val);
                rl[b] = rne_bf16(val - bfbits_to_f(rh[b]));
            }
            const uint4 hh = make_uint4(__builtin_amdgcn_perm(rh[1], rh[0], 0x07060302u),
                                        __builtin_amdgcn_perm(rh[3], rh[2], 0x07060302u),
                                        __builtin_amdgcn_perm(rh[5], rh[4], 0x07060302u),
                                        __builtin_amdgcn_perm(rh[7], rh[6], 0x07060302u));
            const uint4 ll = make_uint4(__builtin_amdgcn_perm(rl[1], rl[0], 0x07060302u),
                                        __builtin_amdgcn_perm(rl[3], rl[2], 0x07060302u),
                                        __builtin_amdgcn_perm(rl[5], rl[4], 0x07060302u),
                                        __builtin_amdgcn_perm(rl[7], rl[6], 0x07060302u));
            *(uint4*)&Ah[by * AOS_ + m * 8] = hh;
            *(uint4*)&Al[by * AOS_ + m * 8] = ll;
        }
    };

    const int fr = lane & 15, fq = lane >> 4;
    f32x4 acc[4][4] = {};

    // ---- prologue ----
    plane_load(0);
    stage_B(0);
    __syncthreads();                         // plane(0)+B(0) landed
    stage_A();                               // A(ch 0)

    for (int cc = 0; cc < NCH_; ++cc) {
        #pragma unroll
        for (int half = 0; half < 2; ++half) {
            const int s = 2 * cc + half;
            __syncthreads();                 // A written / B(s)+plane landed

            // ---- fragments -> registers (conflict-free octet-major) ----
            bf16x8 afh[4], afl[4], bh[4], bl[4];
            #pragma unroll
            for (int i = 0; i < 4; ++i) {
                const int ao = (half * 4 + fq) * AOS_ + (i * 16 + fr) * 8;
                afh[i] = *(const bf16x8*)&Ah[ao];
                afl[i] = *(const bf16x8*)&Al[ao];
            }
            #pragma unroll
            for (int j = 0; j < 4; ++j) {
                const int bo = fq * 2048 + (wid * 64 + j * 16 + fr) * 8;
                bh[j] = *(const bf16x8*)&Bh[bo];
                bl[j] = *(const bf16x8*)&Bl[bo];
            }
            __syncthreads();                 // reads done; LDS reusable

            if (half == 0) {
                stage_B(s + 1);
                if (cc + 1 < NCH_) plane_load(cc + 1);
            } else if (cc + 1 < NCH_) {
                stage_B(s + 1);
                stage_A();                   // A(ch cc+1); plane landed earlier
            }

            #pragma unroll
            for (int j = 0; j < 4; ++j)
                #pragma unroll
                for (int i = 0; i < 4; ++i) {
                    acc[i][j] = __builtin_amdgcn_mfma_f32_16x16x32_bf16(afh[i], bh[j], acc[i][j], 0, 0, 0);
                    acc[i][j] = __builtin_amdgcn_mfma_f32_16x16x32_bf16(afl[i], bh[j], acc[i][j], 0, 0, 0);
                    acc[i][j] = __builtin_amdgcn_mfma_f32_16x16x32_bf16(afh[i], bl[j], acc[i][j], 0, 0, 0);
                }
        }
    }

    // ---- accumulate split partial (C/D: col=lane&15, row=(lane>>4)*4+r) ----
    #pragma unroll
    for (int i = 0; i < 4; ++i) {
        const int row = mi * MT_ + i * 16 + fq * 4;
        #pragma unroll
        for (int j = 0; j < 4; ++j) {
            const int col = wid * 64 + j * 16 + fr;
            #pragma unroll
            for (int r = 0; r < 4; ++r)
                atomicAdd(&z_acc[(size_t)(row + r) * NDF_ + col], acc[i][j][r]);
        }
    }
}

// ---------------------------------------------------------------------------
// Kernel 4: spatial term + soft-assignment clustering.
// ---------------------------------------------------------------------------
__global__ __launch_bounds__(256)
void cluster_kernel(const float* __restrict__ z_acc, const float* __restrict__ bboxs,
                    const float* __restrict__ b_vis, const float* __restrict__ W_spc,
                    const float* __restrict__ b_spc, const float* __restrict__ centT,
                    float* __restrict__ out) {
    const int row = blockIdx.x, t = threadIdx.x;
    __shared__ float zs[NDF_];
    __shared__ float dp[4][KC_];

    const float a = z_acc[(size_t)row * NDF_ + t];

    const float x1 = bboxs[row * 4 + 0], y1 = bboxs[row * 4 + 1];
    const float x2 = bboxs[row * 4 + 2], y2 = bboxs[row * 4 + 3];
    const float cx = x1 + (x2 - x1) * 0.5f - 960.0f;
    const float cy = y1 + (y2 - y1) * 0.5f - 540.0f;
    const float nrm = sqrtf(cx * cx + cy * cy) / sqrtf(960.0f * 960.0f + 540.0f * 540.0f);

    const float zj = a + b_vis[t] + nrm * W_spc[t] + b_spc[t];
    zs[t] = zj;
    out[(size_t)row * NDF_ + t] = zj;                         // output 0: z
    __syncthreads();

    const int k = t & 63, qq = t >> 6;
    {
        float d2 = 0.0f;
        const float* ct = centT + (size_t)qq * 64 * KC_;
        #pragma unroll 8
        for (int j = 0; j < 64; ++j) {
            const float df = zs[qq * 64 + j] - ct[(size_t)j * KC_ + k];
            d2 += df * df;
        }
        dp[qq][k] = d2;
    }
    __syncthreads();

    if (t < 64) {
        const float d = sqrtf(dp[0][t] + dp[1][t] + dp[2][t] + dp[3][t]);
        const float su = 1.0f / (1.0f + d);                   // ALPHA=1
        float sum = su;
        #pragma unroll
        for (int mk = 1; mk < 64; mk <<= 1) sum += __shfl_xor(sum, mk, 64);
        out[(size_t)M_ * NDF_ + (size_t)row * KC_ + t] = su / sum;   // output 1: s
        float v = d; int idx = t;
        #pragma unroll
        for (int mk = 1; mk < 64; mk <<= 1) {
            const float ov = __shfl_xor(v, mk, 64);
            const int oi = __shfl_xor(idx, mk, 64);
            if (ov < v || (ov == v && oi < idx)) { v = ov; idx = oi; }
        }
        if (t == 0)
            out[(size_t)M_ * NDF_ + (size_t)M_ * KC_ + row] = (float)idx;  // output 2: c
    }
}

// ---------------------------------------------------------------------------
extern "C" void kernel_launch(void* const* d_in, const int* in_sizes, int n_in,
                              void* d_out, int out_size, void* d_ws, size_t ws_size,
                              hipStream_t stream) {
    const float* z_vis = (const float*)d_in[0];
    const float* bboxs = (const float*)d_in[1];
    const float* W_vis = (const float*)d_in[2];
    const float* b_vis = (const float*)d_in[3];
    const float* W_spc = (const float*)d_in[4];
    const float* b_spc = (const float*)d_in[5];
    const float* cent  = (const float*)d_in[6];
    float* out = (float*)d_out;

    char* ws = (char*)d_ws;
    unsigned short* Bpack = (unsigned short*)ws;                 // 960*32768 = 31,457,280 B
    float*          centT = (float*)(ws + 31457280);             //     65,536 B
    float*          z_acc = (float*)(ws + 31457280 + 65536);     //  1,048,576 B
    // total ws: ~32.6 MB

    convert_pack<<<KS_ * NSTEP_, 256, 0, stream>>>(W_vis, Bpack);
    convert_cent<<<KC_, 256, 0, stream>>>(cent, centT);
    hipMemsetAsync(z_acc, 0, (size_t)M_ * NDF_ * sizeof(float), stream);
    gemm_fused<<<dim3(KS_, M_ / MT_), 256, 0, stream>>>(z_vis, Bpack, bboxs, z_acc);
    cluster_kernel<<<M_, 256, 0, stream>>>(z_acc, bboxs, b_vis, W_spc, b_spc, centT, out);
}